// Round 1
// baseline (463.351 us; speedup 1.0000x reference)
//
#include <hip/hip_runtime.h>

#define B 8
#define C 64
#define H 256
#define W 256

constexpr int TH = 16, TW = 64;
constexpr int HALO_H = TH + 2, HALO_W = TW + 2;  // 18 x 66

// ---------------------------------------------------------------------------
// Kernel 1: per-pixel score plane  f = 1 + sigmoid( sum_c pw[c]*(dwconv3x3(x_c)+dwb[c]) + pwb )
// f64 accumulation so the later argmax comparison matches a float64 reference
// (discrete selection: tie-flips would cost O(1) absmax otherwise).
// ---------------------------------------------------------------------------
__global__ __launch_bounds__(256) void score_kernel(
    const float* __restrict__ x,      // [B,C,H,W]
    const float* __restrict__ dw_w,   // [C,1,3,3]
    const float* __restrict__ dw_b,   // [C]
    const float* __restrict__ pw_w,   // [1,C,1,1]
    const float* __restrict__ pw_b,   // [1]
    double* __restrict__ fplane)      // [B,H,W]
{
    __shared__ float  xs[HALO_H][HALO_W];
    __shared__ double wc[C][9];
    __shared__ double bias_s;

    const int tid = threadIdx.x;
    const int bw  = blockIdx.x;   // W/TW
    const int bh  = blockIdx.y;   // H/TH
    const int b   = blockIdx.z;   // B

    // Fold pointwise weight into the 9 depthwise taps (f64).
    if (tid < C) {
        double pw = (double)pw_w[tid];
        #pragma unroll
        for (int t = 0; t < 9; ++t)
            wc[tid][t] = pw * (double)dw_w[tid * 9 + t];
    }
    if (tid == 0) {
        double acc = (double)pw_b[0];
        for (int c = 0; c < C; ++c) acc += (double)pw_w[c] * (double)dw_b[c];
        bias_s = acc;
    }

    const int x0c = bw * TW;
    const int y0  = bh * TH;
    const int tx  = tid & 63;   // column within tile
    const int ty4 = tid >> 6;   // 0..3 ; rows ty4 + 4k

    double acc[4] = {0.0, 0.0, 0.0, 0.0};

    const float* xb = x + (size_t)b * C * H * W;

    for (int c = 0; c < C; ++c) {
        const float* xc = xb + (size_t)c * H * W;
        __syncthreads();  // protect xs from previous iteration (and wc on iter 0)
        for (int i = tid; i < HALO_H * HALO_W; i += 256) {
            int r  = i / HALO_W;
            int cc = i - r * HALO_W;
            int gy = y0 + r - 1;
            int gx = x0c + cc - 1;
            float v = 0.0f;
            if ((unsigned)gy < H && (unsigned)gx < W) v = xc[gy * W + gx];
            xs[r][cc] = v;
        }
        __syncthreads();

        const double* w9 = wc[c];
        #pragma unroll
        for (int k = 0; k < 4; ++k) {
            int r = ty4 + 4 * k;
            acc[k] += w9[0] * (double)xs[r    ][tx    ]
                    + w9[1] * (double)xs[r    ][tx + 1]
                    + w9[2] * (double)xs[r    ][tx + 2]
                    + w9[3] * (double)xs[r + 1][tx    ]
                    + w9[4] * (double)xs[r + 1][tx + 1]
                    + w9[5] * (double)xs[r + 1][tx + 2]
                    + w9[6] * (double)xs[r + 2][tx    ]
                    + w9[7] * (double)xs[r + 2][tx + 1]
                    + w9[8] * (double)xs[r + 2][tx + 2];
        }
    }

    const double bias = bias_s;
    double* fp = fplane + (size_t)b * H * W + (size_t)y0 * W + x0c;
    #pragma unroll
    for (int k = 0; k < 4; ++k) {
        int r = ty4 + 4 * k;
        double z = acc[k] + bias;
        double s = 1.0 / (1.0 + exp(-z));
        fp[r * W + tx] = 1.0 + s;
    }
}

// ---------------------------------------------------------------------------
// Kernel 2: selection. block = one (b,y) row; 256 threads = 64 float4-cols x 4
// channel groups. f-row values live in registers, reused over 16 channels.
// ---------------------------------------------------------------------------
__global__ __launch_bounds__(256) void select_kernel(
    const float*  __restrict__ x0,
    const float*  __restrict__ x1,
    const double* __restrict__ f0,
    const double* __restrict__ f1,
    float* __restrict__ out,
    unsigned int* __restrict__ count1)
{
    const int by = blockIdx.x;        // 0 .. B*H-1
    const int b  = by >> 8;           // / H
    const int y  = by & (H - 1);
    const int tx = threadIdx.x & 63;  // float4 column
    const int tc = threadIdx.x >> 6;  // 0..3 channel group

    const size_t plane = (size_t)b * H * W + (size_t)y * W + (size_t)tx * 4;
    double g0[4], g1[4];
    #pragma unroll
    for (int j = 0; j < 4; ++j) { g0[j] = f0[plane + j]; g1[j] = f1[plane + j]; }

    const size_t rowbase = (size_t)b * C * H * W + (size_t)y * W + (size_t)tx * 4;

    unsigned int cnt = 0;
    for (int ci = tc; ci < C; ci += 4) {
        size_t off = rowbase + (size_t)ci * H * W;
        float4 a  = *(const float4*)(x0 + off);
        float4 bb = *(const float4*)(x1 + off);
        float4 r;
        {
            double w0 = (double)a.x * g0[0], w1 = (double)bb.x * g1[0];
            bool sel1 = (w1 > w0); cnt += sel1; r.x = sel1 ? bb.x : a.x;
        }
        {
            double w0 = (double)a.y * g0[1], w1 = (double)bb.y * g1[1];
            bool sel1 = (w1 > w0); cnt += sel1; r.y = sel1 ? bb.y : a.y;
        }
        {
            double w0 = (double)a.z * g0[2], w1 = (double)bb.z * g1[2];
            bool sel1 = (w1 > w0); cnt += sel1; r.z = sel1 ? bb.z : a.z;
        }
        {
            double w0 = (double)a.w * g0[3], w1 = (double)bb.w * g1[3];
            bool sel1 = (w1 > w0); cnt += sel1; r.w = sel1 ? bb.w : a.w;
        }
        *(float4*)(out + off) = r;
    }

    __shared__ unsigned int blk;
    if (threadIdx.x == 0) blk = 0;
    __syncthreads();
    atomicAdd(&blk, cnt);
    __syncthreads();
    if (threadIdx.x == 0) atomicAdd(count1, blk);
}

// ---------------------------------------------------------------------------
// Kernel 3: percentages.
// ---------------------------------------------------------------------------
__global__ void finalize_kernel(const unsigned int* __restrict__ count1,
                                float* __restrict__ out_p)
{
    const double N = (double)B * C * H * W;
    double c1 = (double)(*count1);
    out_p[0] = (float)((N - c1) / N);
    out_p[1] = (float)(c1 / N);
}

extern "C" void kernel_launch(void* const* d_in, const int* in_sizes, int n_in,
                              void* d_out, int out_size, void* d_ws, size_t ws_size,
                              hipStream_t stream) {
    const float* x0    = (const float*)d_in[0];
    const float* x1    = (const float*)d_in[1];
    const float* dw_w0 = (const float*)d_in[2];
    const float* dw_b0 = (const float*)d_in[3];
    const float* pw_w0 = (const float*)d_in[4];
    const float* pw_b0 = (const float*)d_in[5];
    const float* dw_w1 = (const float*)d_in[6];
    const float* dw_b1 = (const float*)d_in[7];
    const float* pw_w1 = (const float*)d_in[8];
    const float* pw_b1 = (const float*)d_in[9];
    float* out = (float*)d_out;

    unsigned int* cnt = (unsigned int*)d_ws;
    double* f0 = (double*)((char*)d_ws + 256);
    double* f1 = f0 + (size_t)B * H * W;

    hipMemsetAsync(d_ws, 0, 256, stream);

    dim3 g1(W / TW, H / TH, B);
    score_kernel<<<g1, 256, 0, stream>>>(x0, dw_w0, dw_b0, pw_w0, pw_b0, f0);
    score_kernel<<<g1, 256, 0, stream>>>(x1, dw_w1, dw_b1, pw_w1, pw_b1, f1);

    select_kernel<<<B * H, 256, 0, stream>>>(x0, x1, f0, f1, out, cnt);

    finalize_kernel<<<1, 1, 0, stream>>>(cnt, out + (size_t)B * C * H * W);
}

// Round 2
// 275.487 us; speedup vs baseline: 1.6819x; 1.6819x over previous
//
#include <hip/hip_runtime.h>

#define B 8
#define C 64
#define H 256
#define W 256

constexpr int TH = 16, TW = 64, CG = 4;
constexpr int HH = TH + 2, HWD = TW + 2;  // halo tile: 18 x 66

// ---------------------------------------------------------------------------
// Fused score kernel: computes f = 1 + sigmoid(score) for BOTH inputs.
// blockIdx.z in [0,16): low 3 bits = batch, bit 3 = which input.
// f64 accumulation so the argmax selection matches the f64 numpy reference
// bit-exactly (discrete selection: one flip costs O(1) absmax).
// ---------------------------------------------------------------------------
__global__ __launch_bounds__(256) void score2_kernel(
    const float* __restrict__ x0, const float* __restrict__ x1,
    const float* __restrict__ dw_w0, const float* __restrict__ dw_b0,
    const float* __restrict__ pw_w0, const float* __restrict__ pw_b0,
    const float* __restrict__ dw_w1, const float* __restrict__ dw_b1,
    const float* __restrict__ pw_w1, const float* __restrict__ pw_b1,
    double* __restrict__ f0, double* __restrict__ f1)
{
    __shared__ float  xs[CG][HH][HWD];   // 19,008 B
    __shared__ double wc[C][9];          //  4,608 B
    __shared__ double bias_s;

    const int tid   = threadIdx.x;
    const int which = blockIdx.z >> 3;
    const int b     = blockIdx.z & 7;

    const float* x    = which ? x1    : x0;
    const float* dw_w = which ? dw_w1 : dw_w0;
    const float* dw_b = which ? dw_b1 : dw_b0;
    const float* pw_w = which ? pw_w1 : pw_w0;
    const float* pw_b = which ? pw_b1 : pw_b0;

    // Fold pointwise weight into the 9 depthwise taps (f64).
    if (tid < C) {
        double pw = (double)pw_w[tid];
        #pragma unroll
        for (int t = 0; t < 9; ++t)
            wc[tid][t] = pw * (double)dw_w[tid * 9 + t];
    }
    if (tid == 0) {
        double acc = (double)pw_b[0];
        for (int c = 0; c < C; ++c) acc += (double)pw_w[c] * (double)dw_b[c];
        bias_s = acc;
    }

    const int x0c = blockIdx.x * TW;
    const int y0  = blockIdx.y * TH;
    const int tx  = tid & 63;          // column within tile
    const int ty4 = (tid >> 6) * 4;    // base output row (owns 4 adjacent rows)

    const float* xp = x + (size_t)b * C * H * W;

    double acc[4] = {0.0, 0.0, 0.0, 0.0};

    for (int r = 0; r < C / CG; ++r) {
        if (r) __syncthreads();  // protect xs from previous round's readers
        // stage CG channel tiles (with halo)
        for (int i = tid; i < CG * HH * HWD; i += 256) {
            int cg  = i / (HH * HWD);
            int rem = i - cg * (HH * HWD);
            int row = rem / HWD;
            int col = rem - row * HWD;
            int gy = y0 + row - 1;
            int gx = x0c + col - 1;
            float v = 0.0f;
            if ((unsigned)gy < H && (unsigned)gx < W)
                v = xp[(size_t)(r * CG + cg) * H * W + gy * W + gx];
            xs[cg][row][col] = v;
        }
        __syncthreads();  // also covers wc/bias_s on round 0

        #pragma unroll
        for (int cg = 0; cg < CG; ++cg) {
            const double* w9 = wc[r * CG + cg];
            // 6 rows x 3 cols window, converted once each
            double d[6][3];
            #pragma unroll
            for (int rr = 0; rr < 6; ++rr)
                #pragma unroll
                for (int cc = 0; cc < 3; ++cc)
                    d[rr][cc] = (double)xs[cg][ty4 + rr][tx + cc];
            #pragma unroll
            for (int k = 0; k < 4; ++k)
                #pragma unroll
                for (int tr = 0; tr < 3; ++tr)
                    #pragma unroll
                    for (int tc = 0; tc < 3; ++tc)
                        acc[k] += w9[3 * tr + tc] * d[k + tr][tc];
        }
    }

    const double bias = bias_s;
    double* fp = (which ? f1 : f0) + (size_t)b * H * W + (size_t)y0 * W + x0c;
    #pragma unroll
    for (int k = 0; k < 4; ++k) {
        double z = acc[k] + bias;
        double s = 1.0 / (1.0 + exp(-z));
        fp[(ty4 + k) * W + tx] = 1.0 + s;
    }
}

// ---------------------------------------------------------------------------
// Selection. block = one (b,y) row; 256 threads = 64 float4-cols x 4 channel
// groups. f-row values live in registers, reused over 16 channels.
// ---------------------------------------------------------------------------
__global__ __launch_bounds__(256) void select_kernel(
    const float*  __restrict__ x0,
    const float*  __restrict__ x1,
    const double* __restrict__ f0,
    const double* __restrict__ f1,
    float* __restrict__ out,
    unsigned int* __restrict__ count1)
{
    const int by = blockIdx.x;        // 0 .. B*H-1
    const int b  = by >> 8;           // / H
    const int y  = by & (H - 1);
    const int tx = threadIdx.x & 63;  // float4 column
    const int tc = threadIdx.x >> 6;  // 0..3 channel group

    const size_t plane = (size_t)b * H * W + (size_t)y * W + (size_t)tx * 4;
    double g0[4], g1[4];
    #pragma unroll
    for (int j = 0; j < 4; ++j) { g0[j] = f0[plane + j]; g1[j] = f1[plane + j]; }

    const size_t rowbase = (size_t)b * C * H * W + (size_t)y * W + (size_t)tx * 4;

    unsigned int cnt = 0;
    for (int ci = tc; ci < C; ci += 4) {
        size_t off = rowbase + (size_t)ci * H * W;
        float4 a  = *(const float4*)(x0 + off);
        float4 bb = *(const float4*)(x1 + off);
        float4 r;
        {
            double w0 = (double)a.x * g0[0], w1 = (double)bb.x * g1[0];
            bool sel1 = (w1 > w0); cnt += sel1; r.x = sel1 ? bb.x : a.x;
        }
        {
            double w0 = (double)a.y * g0[1], w1 = (double)bb.y * g1[1];
            bool sel1 = (w1 > w0); cnt += sel1; r.y = sel1 ? bb.y : a.y;
        }
        {
            double w0 = (double)a.z * g0[2], w1 = (double)bb.z * g1[2];
            bool sel1 = (w1 > w0); cnt += sel1; r.z = sel1 ? bb.z : a.z;
        }
        {
            double w0 = (double)a.w * g0[3], w1 = (double)bb.w * g1[3];
            bool sel1 = (w1 > w0); cnt += sel1; r.w = sel1 ? bb.w : a.w;
        }
        *(float4*)(out + off) = r;
    }

    __shared__ unsigned int blk;
    if (threadIdx.x == 0) blk = 0;
    __syncthreads();
    atomicAdd(&blk, cnt);
    __syncthreads();
    if (threadIdx.x == 0) atomicAdd(count1, blk);
}

// ---------------------------------------------------------------------------
// Percentages.
// ---------------------------------------------------------------------------
__global__ void finalize_kernel(const unsigned int* __restrict__ count1,
                                float* __restrict__ out_p)
{
    const double N = (double)B * C * H * W;
    double c1 = (double)(*count1);
    out_p[0] = (float)((N - c1) / N);
    out_p[1] = (float)(c1 / N);
}

extern "C" void kernel_launch(void* const* d_in, const int* in_sizes, int n_in,
                              void* d_out, int out_size, void* d_ws, size_t ws_size,
                              hipStream_t stream) {
    const float* x0    = (const float*)d_in[0];
    const float* x1    = (const float*)d_in[1];
    const float* dw_w0 = (const float*)d_in[2];
    const float* dw_b0 = (const float*)d_in[3];
    const float* pw_w0 = (const float*)d_in[4];
    const float* pw_b0 = (const float*)d_in[5];
    const float* dw_w1 = (const float*)d_in[6];
    const float* dw_b1 = (const float*)d_in[7];
    const float* pw_w1 = (const float*)d_in[8];
    const float* pw_b1 = (const float*)d_in[9];
    float* out = (float*)d_out;

    unsigned int* cnt = (unsigned int*)d_ws;
    double* f0 = (double*)((char*)d_ws + 256);
    double* f1 = f0 + (size_t)B * H * W;

    hipMemsetAsync(d_ws, 0, 256, stream);

    dim3 g1(W / TW, H / TH, 2 * B);   // 4 x 16 x 16 = 1024 blocks
    score2_kernel<<<g1, 256, 0, stream>>>(x0, x1,
                                          dw_w0, dw_b0, pw_w0, pw_b0,
                                          dw_w1, dw_b1, pw_w1, pw_b1,
                                          f0, f1);

    select_kernel<<<B * H, 256, 0, stream>>>(x0, x1, f0, f1, out, cnt);

    finalize_kernel<<<1, 1, 0, stream>>>(cnt, out + (size_t)B * C * H * W);
}

// Round 3
// 206.304 us; speedup vs baseline: 2.2460x; 1.3353x over previous
//
#include <hip/hip_runtime.h>
#include <math.h>

#define B 8
#define C 64
#define H 256
#define W 256
#define NPLANE 16            // 2 inputs x 8 batches
#define PSZ (H * W)          // 65536

// workspace layout
#define OFF_CNT   0
#define OFF_WC    256                       // 2*64*9 f64 = 9216 B
#define OFF_BIAS  9472                      // 2 f64
#define OFF_HZ    16384                     // 3*16*PSZ f64 = 25165824 B
#define OFF_F     (16384 + 25165824)        // 16*PSZ f64 = 8388608 B
#define WS_NEED   (OFF_F + 16ull * PSZ * 8)

// ---------------------------------------------------------------------------
// prep: fold pointwise weight into depthwise taps (f64), fold biases.
// ---------------------------------------------------------------------------
__global__ void prep_kernel(const float* __restrict__ dw_w0, const float* __restrict__ dw_b0,
                            const float* __restrict__ pw_w0, const float* __restrict__ pw_b0,
                            const float* __restrict__ dw_w1, const float* __restrict__ dw_b1,
                            const float* __restrict__ pw_w1, const float* __restrict__ pw_b1,
                            double* __restrict__ wc, double* __restrict__ bias)
{
    int t = threadIdx.x;            // 0..127
    int which = t >> 6, c = t & 63;
    const float* dw = which ? dw_w1 : dw_w0;
    const float* pw = which ? pw_w1 : pw_w0;
    double p = (double)pw[c];
    #pragma unroll
    for (int k = 0; k < 9; ++k)
        wc[(which * 64 + c) * 9 + k] = p * (double)dw[c * 9 + k];
    if (c == 0) {
        const float* dwb = which ? dw_b1 : dw_b0;
        const float* pwb = which ? pw_b1 : pw_b0;
        double acc = (double)pwb[0];
        for (int cc = 0; cc < 64; ++cc) acc += (double)pw[cc] * (double)dwb[cc];
        bias[which] = acc;
    }
}

// ---------------------------------------------------------------------------
// hz pass: pure streaming, no LDS, no barriers. One wave = one image row.
// lane owns 4 columns (float4); x-halo via 2 shuffles; accumulates the three
// horizontal tap-sums hz_i (f64) over all 64 channels; writes 3 tap-planes.
// ---------------------------------------------------------------------------
__global__ __launch_bounds__(256) void hz_kernel(
    const float* __restrict__ x0, const float* __restrict__ x1,
    const double* __restrict__ wc, double* __restrict__ hz)
{
    const int lane = threadIdx.x & 63;
    const int wid  = (blockIdx.x * blockDim.x + threadIdx.x) >> 6;   // 0..2047

    for (int t = wid; t < NPLANE * H; t += 2048) {
        const int p     = t >> 8;
        const int y     = t & 255;
        const int which = p >> 3;
        const float* xr = (which ? x1 : x0) + (size_t)(p & 7) * C * PSZ + y * W + lane * 4;
        const double* wp = wc + which * 64 * 9;

        double hzv[3][4] = {};

        #pragma unroll 2
        for (int c = 0; c < C; ++c) {
            float4 v = *(const float4*)(xr + (size_t)c * PSZ);
            float lf = __shfl_up(v.w, 1);
            float rf = __shfl_down(v.x, 1);
            if (lane == 0)  lf = 0.0f;
            if (lane == 63) rf = 0.0f;
            double dd[6] = {(double)lf, (double)v.x, (double)v.y,
                            (double)v.z, (double)v.w, (double)rf};
            const double* w9 = wp + c * 9;
            #pragma unroll
            for (int i = 0; i < 3; ++i) {
                double w0 = w9[3 * i], w1 = w9[3 * i + 1], w2 = w9[3 * i + 2];
                #pragma unroll
                for (int k = 0; k < 4; ++k)
                    hzv[i][k] += w0 * dd[k] + w1 * dd[k + 1] + w2 * dd[k + 2];
            }
        }

        #pragma unroll
        for (int i = 0; i < 3; ++i) {
            double* o = hz + ((size_t)i * NPLANE + p) * PSZ + y * W + lane * 4;
            o[0] = hzv[i][0]; o[1] = hzv[i][1]; o[2] = hzv[i][2]; o[3] = hzv[i][3];
        }
    }
}

// ---------------------------------------------------------------------------
// fscore: vertical combine + sigmoid.  f = 1 + sigmoid(hz0[y-1]+hz1[y]+hz2[y+1]+bias)
// ---------------------------------------------------------------------------
__global__ __launch_bounds__(256) void fscore_kernel(
    const double* __restrict__ hz, const double* __restrict__ bias,
    double* __restrict__ f)
{
    int idx = blockIdx.x * 256 + threadIdx.x;   // 0 .. 16*PSZ-1
    int p  = idx >> 16;
    int yx = idx & 65535;
    int y  = yx >> 8;
    double acc = bias[p >> 3];
    if (y > 0)     acc += hz[((size_t)0 * NPLANE + p) * PSZ + yx - W];
    acc += hz[((size_t)1 * NPLANE + p) * PSZ + yx];
    if (y < H - 1) acc += hz[((size_t)2 * NPLANE + p) * PSZ + yx + W];
    double s = 1.0 / (1.0 + exp(-acc));
    f[idx] = 1.0 + s;
}

// ---------------------------------------------------------------------------
// FALLBACK score kernel (round-2 structure) — used only if ws_size < WS_NEED.
// ---------------------------------------------------------------------------
constexpr int TH = 16, TW = 64, CG = 4;
constexpr int HH = TH + 2, HWD = TW + 2;

__global__ __launch_bounds__(256) void score2_kernel(
    const float* __restrict__ x0, const float* __restrict__ x1,
    const float* __restrict__ dw_w0, const float* __restrict__ dw_b0,
    const float* __restrict__ pw_w0, const float* __restrict__ pw_b0,
    const float* __restrict__ dw_w1, const float* __restrict__ dw_b1,
    const float* __restrict__ pw_w1, const float* __restrict__ pw_b1,
    double* __restrict__ f0, double* __restrict__ f1)
{
    __shared__ float  xs[CG][HH][HWD];
    __shared__ double wcs[C][9];
    __shared__ double bias_s;

    const int tid   = threadIdx.x;
    const int which = blockIdx.z >> 3;
    const int b     = blockIdx.z & 7;

    const float* x    = which ? x1    : x0;
    const float* dw_w = which ? dw_w1 : dw_w0;
    const float* dw_b = which ? dw_b1 : dw_b0;
    const float* pw_w = which ? pw_w1 : pw_w0;
    const float* pw_b = which ? pw_b1 : pw_b0;

    if (tid < C) {
        double pw = (double)pw_w[tid];
        #pragma unroll
        for (int t = 0; t < 9; ++t) wcs[tid][t] = pw * (double)dw_w[tid * 9 + t];
    }
    if (tid == 0) {
        double acc = (double)pw_b[0];
        for (int c = 0; c < C; ++c) acc += (double)pw_w[c] * (double)dw_b[c];
        bias_s = acc;
    }

    const int x0c = blockIdx.x * TW;
    const int y0  = blockIdx.y * TH;
    const int tx  = tid & 63;
    const int ty4 = (tid >> 6) * 4;

    const float* xp = x + (size_t)b * C * H * W;
    double acc[4] = {0.0, 0.0, 0.0, 0.0};

    for (int r = 0; r < C / CG; ++r) {
        if (r) __syncthreads();
        for (int i = tid; i < CG * HH * HWD; i += 256) {
            int cg  = i / (HH * HWD);
            int rem = i - cg * (HH * HWD);
            int row = rem / HWD;
            int col = rem - row * HWD;
            int gy = y0 + row - 1;
            int gx = x0c + col - 1;
            float v = 0.0f;
            if ((unsigned)gy < H && (unsigned)gx < W)
                v = xp[(size_t)(r * CG + cg) * H * W + gy * W + gx];
            xs[cg][row][col] = v;
        }
        __syncthreads();

        #pragma unroll
        for (int cg = 0; cg < CG; ++cg) {
            const double* w9 = wcs[r * CG + cg];
            double d[6][3];
            #pragma unroll
            for (int rr = 0; rr < 6; ++rr)
                #pragma unroll
                for (int cc = 0; cc < 3; ++cc)
                    d[rr][cc] = (double)xs[cg][ty4 + rr][tx + cc];
            #pragma unroll
            for (int k = 0; k < 4; ++k)
                #pragma unroll
                for (int tr = 0; tr < 3; ++tr)
                    #pragma unroll
                    for (int tc = 0; tc < 3; ++tc)
                        acc[k] += w9[3 * tr + tc] * d[k + tr][tc];
        }
    }

    const double bias = bias_s;
    double* fp = (which ? f1 : f0) + (size_t)b * H * W + (size_t)y0 * W + x0c;
    #pragma unroll
    for (int k = 0; k < 4; ++k) {
        double z = acc[k] + bias;
        double s = 1.0 / (1.0 + exp(-z));
        fp[(ty4 + k) * W + tx] = 1.0 + s;
    }
}

// ---------------------------------------------------------------------------
// Selection. block = one (b,y) row; 256 threads = 64 float4-cols x 4 channel
// groups. f-row values live in registers, reused over 16 channels.
// ---------------------------------------------------------------------------
__global__ __launch_bounds__(256) void select_kernel(
    const float*  __restrict__ x0,
    const float*  __restrict__ x1,
    const double* __restrict__ f0,
    const double* __restrict__ f1,
    float* __restrict__ out,
    unsigned int* __restrict__ count1)
{
    const int by = blockIdx.x;
    const int b  = by >> 8;
    const int y  = by & (H - 1);
    const int tx = threadIdx.x & 63;
    const int tc = threadIdx.x >> 6;

    const size_t plane = (size_t)b * H * W + (size_t)y * W + (size_t)tx * 4;
    double g0[4], g1[4];
    #pragma unroll
    for (int j = 0; j < 4; ++j) { g0[j] = f0[plane + j]; g1[j] = f1[plane + j]; }

    const size_t rowbase = (size_t)b * C * H * W + (size_t)y * W + (size_t)tx * 4;

    unsigned int cnt = 0;
    for (int ci = tc; ci < C; ci += 4) {
        size_t off = rowbase + (size_t)ci * H * W;
        float4 a  = *(const float4*)(x0 + off);
        float4 bb = *(const float4*)(x1 + off);
        float4 r;
        { double w0=(double)a.x*g0[0], w1=(double)bb.x*g1[0]; bool s1=(w1>w0); cnt+=s1; r.x=s1?bb.x:a.x; }
        { double w0=(double)a.y*g0[1], w1=(double)bb.y*g1[1]; bool s1=(w1>w0); cnt+=s1; r.y=s1?bb.y:a.y; }
        { double w0=(double)a.z*g0[2], w1=(double)bb.z*g1[2]; bool s1=(w1>w0); cnt+=s1; r.z=s1?bb.z:a.z; }
        { double w0=(double)a.w*g0[3], w1=(double)bb.w*g1[3]; bool s1=(w1>w0); cnt+=s1; r.w=s1?bb.w:a.w; }
        *(float4*)(out + off) = r;
    }

    __shared__ unsigned int blk;
    if (threadIdx.x == 0) blk = 0;
    __syncthreads();
    atomicAdd(&blk, cnt);
    __syncthreads();
    if (threadIdx.x == 0) atomicAdd(count1, blk);
}

__global__ void finalize_kernel(const unsigned int* __restrict__ count1,
                                float* __restrict__ out_p)
{
    const double N = (double)B * C * H * W;
    double c1 = (double)(*count1);
    out_p[0] = (float)((N - c1) / N);
    out_p[1] = (float)(c1 / N);
}

extern "C" void kernel_launch(void* const* d_in, const int* in_sizes, int n_in,
                              void* d_out, int out_size, void* d_ws, size_t ws_size,
                              hipStream_t stream) {
    const float* x0    = (const float*)d_in[0];
    const float* x1    = (const float*)d_in[1];
    const float* dw_w0 = (const float*)d_in[2];
    const float* dw_b0 = (const float*)d_in[3];
    const float* pw_w0 = (const float*)d_in[4];
    const float* pw_b0 = (const float*)d_in[5];
    const float* dw_w1 = (const float*)d_in[6];
    const float* dw_b1 = (const float*)d_in[7];
    const float* pw_w1 = (const float*)d_in[8];
    const float* pw_b1 = (const float*)d_in[9];
    float* out = (float*)d_out;

    unsigned int* cnt = (unsigned int*)d_ws;
    hipMemsetAsync(d_ws, 0, 256, stream);

    if (ws_size >= WS_NEED) {
        double* wc   = (double*)((char*)d_ws + OFF_WC);
        double* bias = (double*)((char*)d_ws + OFF_BIAS);
        double* hz   = (double*)((char*)d_ws + OFF_HZ);
        double* f    = (double*)((char*)d_ws + OFF_F);
        double* f0   = f;
        double* f1   = f + (size_t)8 * PSZ;

        prep_kernel<<<1, 128, 0, stream>>>(dw_w0, dw_b0, pw_w0, pw_b0,
                                           dw_w1, dw_b1, pw_w1, pw_b1, wc, bias);
        hz_kernel<<<512, 256, 0, stream>>>(x0, x1, wc, hz);
        fscore_kernel<<<NPLANE * PSZ / 256, 256, 0, stream>>>(hz, bias, f);
        select_kernel<<<B * H, 256, 0, stream>>>(x0, x1, f0, f1, out, cnt);
    } else {
        double* f0 = (double*)((char*)d_ws + 256);
        double* f1 = f0 + (size_t)B * H * W;
        dim3 g1(W / TW, H / TH, 2 * B);
        score2_kernel<<<g1, 256, 0, stream>>>(x0, x1,
                                              dw_w0, dw_b0, pw_w0, pw_b0,
                                              dw_w1, dw_b1, pw_w1, pw_b1, f0, f1);
        select_kernel<<<B * H, 256, 0, stream>>>(x0, x1, f0, f1, out, cnt);
    }

    finalize_kernel<<<1, 1, 0, stream>>>(cnt, out + (size_t)B * C * H * W);
}

// Round 4
// 162.425 us; speedup vs baseline: 2.8527x; 1.2701x over previous
//
#include <hip/hip_runtime.h>
#include <math.h>

#define B 8
#define C 64
#define H 256
#define W 256
#define NPLANE 16            // 2 inputs x 8 batches
#define PSZ (H * W)          // 65536

// workspace layout
#define OFF_WC    256                        // 2*64*9 f64 = 9216 B
#define OFF_BIAS  9728                       // 2 f64
#define OFF_F     16384                      // 16*PSZ f64 = 8388608 B

// ---------------------------------------------------------------------------
// prep: fold pointwise weight into depthwise taps (f64), fold biases.
// ---------------------------------------------------------------------------
__global__ void prep_kernel(const float* __restrict__ dw_w0, const float* __restrict__ dw_b0,
                            const float* __restrict__ pw_w0, const float* __restrict__ pw_b0,
                            const float* __restrict__ dw_w1, const float* __restrict__ dw_b1,
                            const float* __restrict__ pw_w1, const float* __restrict__ pw_b1,
                            double* __restrict__ wc, double* __restrict__ bias)
{
    int t = threadIdx.x;            // 0..127
    int which = t >> 6, c = t & 63;
    const float* dw = which ? dw_w1 : dw_w0;
    const float* pw = which ? pw_w1 : pw_w0;
    double p = (double)pw[c];
    #pragma unroll
    for (int k = 0; k < 9; ++k)
        wc[(which * 64 + c) * 9 + k] = p * (double)dw[c * 9 + k];
    if (c == 0) {
        const float* dwb = which ? dw_b1 : dw_b0;
        const float* pwb = which ? pw_b1 : pw_b0;
        double acc = (double)pwb[0];
        for (int cc = 0; cc < 64; ++cc) acc += (double)pw[cc] * (double)dwb[cc];
        bias[which] = acc;
    }
}

// ---------------------------------------------------------------------------
// score: block = (plane, 4-row band). 4 waves x 16 channels each.
// Per channel: load the 6 halo rows (float4/lane), horizontal taps via
// 2 shuffles, accumulate all 12 (row, weight-row) variants in f64.
// One LDS reduction (fixed order -> deterministic), sigmoid, write f.
// f64 end-to-end so the argmax selection matches the f64 numpy reference
// (discrete selection: one flip costs O(1) absmax).
// ---------------------------------------------------------------------------
__global__ __launch_bounds__(256, 4) void score_band_kernel(
    const float* __restrict__ x0, const float* __restrict__ x1,
    const double* __restrict__ wc, const double* __restrict__ bias,
    double* __restrict__ f)
{
    // XCD-bijective swizzle: adjacent bands land on the same XCD (L2 halo reuse).
    // 1024 blocks, 8 XCDs, 128 per XCD.
    const int n    = blockIdx.x;
    const int task = (n & 7) * 128 + (n >> 3);
    const int plane = task >> 6;         // 0..15
    const int band  = task & 63;         // 0..63
    const int which = plane >> 3;
    const int b     = plane & 7;
    const int y0    = band * 4;

    const int w    = threadIdx.x >> 6;   // wave 0..3
    const int lane = threadIdx.x & 63;

    const float*  xp = (which ? x1 : x0) + (size_t)b * C * PSZ;
    const double* wp = wc + which * (64 * 9);

    double acc[4][4] = {};   // [out-row][px]

    #pragma unroll 2
    for (int cc = 0; cc < 16; ++cc) {
        const int c = w * 16 + cc;
        const float* xc = xp + (size_t)c * PSZ + lane * 4;

        // issue the 6 halo-row loads together (rows y0-1 .. y0+4)
        float4 rv[6];
        #pragma unroll
        for (int j = 0; j < 6; ++j) {
            int r = y0 - 1 + j;
            if ((unsigned)r < H) rv[j] = *(const float4*)(xc + (size_t)r * W);
            else                 rv[j] = make_float4(0.f, 0.f, 0.f, 0.f);
        }

        double w9[9];
        #pragma unroll
        for (int t = 0; t < 9; ++t) w9[t] = wp[c * 9 + t];

        #pragma unroll
        for (int j = 0; j < 6; ++j) {
            float lf = __shfl_up(rv[j].w, 1);
            float rf = __shfl_down(rv[j].x, 1);
            if (lane == 0)  lf = 0.0f;
            if (lane == 63) rf = 0.0f;
            double dd[6] = {(double)lf, (double)rv[j].x, (double)rv[j].y,
                            (double)rv[j].z, (double)rv[j].w, (double)rf};
            // input row r = y0-1+j contributes to out-row o = j - i with weight row i
            #pragma unroll
            for (int i = 0; i < 3; ++i) {
                const int o = j - i;
                if (o >= 0 && o < 4) {
                    double wa = w9[3 * i], wb = w9[3 * i + 1], wcv = w9[3 * i + 2];
                    #pragma unroll
                    for (int k = 0; k < 4; ++k)
                        acc[o][k] += wa * dd[k] + wb * dd[k + 1] + wcv * dd[k + 2];
                }
            }
        }
    }

    // deterministic cross-wave reduction
    __shared__ double sred[4][4][W];   // [wave][row][px] = 32 KiB
    #pragma unroll
    for (int o = 0; o < 4; ++o)
        #pragma unroll
        for (int k = 0; k < 4; ++k)
            sred[w][o][lane * 4 + k] = acc[o][k];
    __syncthreads();

    const int row = threadIdx.x >> 6;        // 0..3
    const int px  = (threadIdx.x & 63) * 4;
    const double bv = bias[which];
    double* fp = f + (size_t)plane * PSZ + (size_t)(y0 + row) * W + px;
    #pragma unroll
    for (int k = 0; k < 4; ++k) {
        double s = sred[0][row][px + k] + sred[1][row][px + k]
                 + sred[2][row][px + k] + sred[3][row][px + k] + bv;
        fp[k] = 1.0 + 1.0 / (1.0 + exp(-s));
    }
}

// ---------------------------------------------------------------------------
// Selection. block = one (b,y) row; 256 threads = 64 float4-cols x 4 channel
// groups. f-row values live in registers, reused over 16 channels.
// ---------------------------------------------------------------------------
__global__ __launch_bounds__(256) void select_kernel(
    const float*  __restrict__ x0,
    const float*  __restrict__ x1,
    const double* __restrict__ f0,
    const double* __restrict__ f1,
    float* __restrict__ out,
    unsigned int* __restrict__ count1)
{
    const int by = blockIdx.x;        // 0 .. B*H-1
    const int b  = by >> 8;
    const int y  = by & (H - 1);
    const int tx = threadIdx.x & 63;
    const int tc = threadIdx.x >> 6;

    const size_t plane = (size_t)b * H * W + (size_t)y * W + (size_t)tx * 4;
    double g0[4], g1[4];
    #pragma unroll
    for (int j = 0; j < 4; ++j) { g0[j] = f0[plane + j]; g1[j] = f1[plane + j]; }

    const size_t rowbase = (size_t)b * C * H * W + (size_t)y * W + (size_t)tx * 4;

    unsigned int cnt = 0;
    for (int ci = tc; ci < C; ci += 4) {
        size_t off = rowbase + (size_t)ci * H * W;
        float4 a  = *(const float4*)(x0 + off);
        float4 bb = *(const float4*)(x1 + off);
        float4 r;
        { double w0=(double)a.x*g0[0], w1=(double)bb.x*g1[0]; bool s1=(w1>w0); cnt+=s1; r.x=s1?bb.x:a.x; }
        { double w0=(double)a.y*g0[1], w1=(double)bb.y*g1[1]; bool s1=(w1>w0); cnt+=s1; r.y=s1?bb.y:a.y; }
        { double w0=(double)a.z*g0[2], w1=(double)bb.z*g1[2]; bool s1=(w1>w0); cnt+=s1; r.z=s1?bb.z:a.z; }
        { double w0=(double)a.w*g0[3], w1=(double)bb.w*g1[3]; bool s1=(w1>w0); cnt+=s1; r.w=s1?bb.w:a.w; }
        *(float4*)(out + off) = r;
    }

    __shared__ unsigned int blk;
    if (threadIdx.x == 0) blk = 0;
    __syncthreads();
    atomicAdd(&blk, cnt);
    __syncthreads();
    if (threadIdx.x == 0) atomicAdd(count1, blk);
}

__global__ void finalize_kernel(const unsigned int* __restrict__ count1,
                                float* __restrict__ out_p)
{
    const double N = (double)B * C * H * W;
    double c1 = (double)(*count1);
    out_p[0] = (float)((N - c1) / N);
    out_p[1] = (float)(c1 / N);
}

extern "C" void kernel_launch(void* const* d_in, const int* in_sizes, int n_in,
                              void* d_out, int out_size, void* d_ws, size_t ws_size,
                              hipStream_t stream) {
    const float* x0    = (const float*)d_in[0];
    const float* x1    = (const float*)d_in[1];
    const float* dw_w0 = (const float*)d_in[2];
    const float* dw_b0 = (const float*)d_in[3];
    const float* pw_w0 = (const float*)d_in[4];
    const float* pw_b0 = (const float*)d_in[5];
    const float* dw_w1 = (const float*)d_in[6];
    const float* dw_b1 = (const float*)d_in[7];
    const float* pw_w1 = (const float*)d_in[8];
    const float* pw_b1 = (const float*)d_in[9];
    float* out = (float*)d_out;

    unsigned int* cnt  = (unsigned int*)d_ws;
    double*       wc   = (double*)((char*)d_ws + OFF_WC);
    double*       bias = (double*)((char*)d_ws + OFF_BIAS);
    double*       f    = (double*)((char*)d_ws + OFF_F);
    double*       f0   = f;                       // planes 0..7  (input 0)
    double*       f1   = f + (size_t)8 * PSZ;     // planes 8..15 (input 1)

    hipMemsetAsync(d_ws, 0, 256, stream);

    prep_kernel<<<1, 128, 0, stream>>>(dw_w0, dw_b0, pw_w0, pw_b0,
                                       dw_w1, dw_b1, pw_w1, pw_b1, wc, bias);

    score_band_kernel<<<NPLANE * (H / 4), 256, 0, stream>>>(x0, x1, wc, bias, f);

    select_kernel<<<B * H, 256, 0, stream>>>(x0, x1, f0, f1, out, cnt);

    finalize_kernel<<<1, 1, 0, stream>>>(cnt, out + (size_t)B * C * H * W);
}

// Round 5
// 149.895 us; speedup vs baseline: 3.0912x; 1.0836x over previous
//
#include <hip/hip_runtime.h>
#include <math.h>

#define B 8
#define C 64
#define H 256
#define W 256
#define NPLANE 16            // 2 inputs x 8 batches
#define PSZ (H * W)          // 65536

// workspace layout
#define OFF_WC    256                        // 2*64*9 f64 = 9216 B
#define OFF_BIAS  9728                       // 2 f64
#define OFF_F     16384                      // 16*PSZ f64 = 8388608 B

// ---------------------------------------------------------------------------
// prep: fold pointwise weight into depthwise taps (f64), fold biases.
// ---------------------------------------------------------------------------
__global__ void prep_kernel(const float* __restrict__ dw_w0, const float* __restrict__ dw_b0,
                            const float* __restrict__ pw_w0, const float* __restrict__ pw_b0,
                            const float* __restrict__ dw_w1, const float* __restrict__ dw_b1,
                            const float* __restrict__ pw_w1, const float* __restrict__ pw_b1,
                            double* __restrict__ wc, double* __restrict__ bias)
{
    int t = threadIdx.x;            // 0..127
    int which = t >> 6, c = t & 63;
    const float* dw = which ? dw_w1 : dw_w0;
    const float* pw = which ? pw_w1 : pw_w0;
    double p = (double)pw[c];
    #pragma unroll
    for (int k = 0; k < 9; ++k)
        wc[(which * 64 + c) * 9 + k] = p * (double)dw[c * 9 + k];
    if (c == 0) {
        const float* dwb = which ? dw_b1 : dw_b0;
        const float* pwb = which ? pw_b1 : pw_b0;
        double acc = (double)pwb[0];
        for (int cc = 0; cc < 64; ++cc) acc += (double)pw[cc] * (double)dwb[cc];
        bias[which] = acc;
    }
}

// ---------------------------------------------------------------------------
// score: block = (plane, 4-row band). 4 waves x 16 channels each.
// Explicit 2-deep channel pipeline: issue next channel's 6 halo-row loads
// before computing current channel (needs VGPR headroom -> bounds(256,2);
// round-4's bounds(256,4) squeezed VGPR to 64 and serialized every load).
// f64 end-to-end so the argmax selection matches the f64 numpy reference.
// ---------------------------------------------------------------------------
__global__ __launch_bounds__(256, 2) void score_band_kernel(
    const float* __restrict__ x0, const float* __restrict__ x1,
    const double* __restrict__ wc, const double* __restrict__ bias,
    double* __restrict__ f)
{
    __shared__ double swc[C * 9];        // 4,608 B folded weights
    __shared__ double sred[4][4][4][64]; // [wave][row][k][lane] = 32 KiB

    // XCD-bijective swizzle: adjacent bands land on the same XCD (L2 halo reuse).
    const int n     = blockIdx.x;
    const int task  = (n & 7) * 128 + (n >> 3);
    const int plane = task >> 6;         // 0..15
    const int band  = task & 63;         // 0..63
    const int which = plane >> 3;
    const int b     = plane & 7;
    const int y0    = band * 4;

    const int w    = threadIdx.x >> 6;   // wave 0..3
    const int lane = threadIdx.x & 63;

    // stage folded weights once per block
    const double* wp = wc + which * (C * 9);
    for (int i = threadIdx.x; i < C * 9; i += 256) swc[i] = wp[i];
    __syncthreads();

    const float* xp = (which ? x1 : x0) + (size_t)b * C * PSZ
                    + (size_t)y0 * W + lane * 4;
    const bool interior = (band != 0) && (band != 63);

    double acc[4][4] = {};   // [out-row][px]
    const int cbase = w * 16;

    float4 a0, a1, a2, a3, a4, a5;   // current channel rows y0-1 .. y0+4
    float4 n0, n1, n2, n3, n4, n5;   // prefetched next channel

#define LOADROWS(cidx, r0, r1, r2, r3, r4, r5)                                 \
    {                                                                          \
        const float* p_ = xp + (size_t)(cidx) * PSZ;                           \
        if (interior) {                                                        \
            r0 = *(const float4*)(p_ - W);                                     \
            r1 = *(const float4*)(p_);                                         \
            r2 = *(const float4*)(p_ + W);                                     \
            r3 = *(const float4*)(p_ + 2 * W);                                 \
            r4 = *(const float4*)(p_ + 3 * W);                                 \
            r5 = *(const float4*)(p_ + 4 * W);                                 \
        } else {                                                               \
            const float4 z_ = make_float4(0.f, 0.f, 0.f, 0.f);                 \
            r0 = (band != 0)  ? *(const float4*)(p_ - W)     : z_;             \
            r1 = *(const float4*)(p_);                                         \
            r2 = *(const float4*)(p_ + W);                                     \
            r3 = *(const float4*)(p_ + 2 * W);                                 \
            r4 = *(const float4*)(p_ + 3 * W);                                 \
            r5 = (band != 63) ? *(const float4*)(p_ + 4 * W) : z_;             \
        }                                                                      \
    }

#define COMPUTE(cidx, r0, r1, r2, r3, r4, r5)                                  \
    {                                                                          \
        double w9_[9];                                                         \
        _Pragma("unroll")                                                      \
        for (int t_ = 0; t_ < 9; ++t_) w9_[t_] = swc[(cidx) * 9 + t_];         \
        const float4 rr_[6] = {r0, r1, r2, r3, r4, r5};                        \
        _Pragma("unroll")                                                      \
        for (int j_ = 0; j_ < 6; ++j_) {                                       \
            float lf_ = __shfl_up(rr_[j_].w, 1);                               \
            float rf_ = __shfl_down(rr_[j_].x, 1);                             \
            if (lane == 0)  lf_ = 0.0f;                                        \
            if (lane == 63) rf_ = 0.0f;                                        \
            double dd_[6] = {(double)lf_, (double)rr_[j_].x, (double)rr_[j_].y,\
                             (double)rr_[j_].z, (double)rr_[j_].w, (double)rf_};\
            _Pragma("unroll")                                                  \
            for (int i_ = 0; i_ < 3; ++i_) {                                   \
                const int o_ = j_ - i_;                                        \
                if (o_ >= 0 && o_ < 4) {                                       \
                    double wa_ = w9_[3 * i_], wb_ = w9_[3 * i_ + 1],           \
                           wc_ = w9_[3 * i_ + 2];                              \
                    _Pragma("unroll")                                          \
                    for (int k_ = 0; k_ < 4; ++k_)                             \
                        acc[o_][k_] += wa_ * dd_[k_] + wb_ * dd_[k_ + 1]       \
                                     + wc_ * dd_[k_ + 2];                      \
                }                                                              \
            }                                                                  \
        }                                                                      \
    }

    LOADROWS(cbase, a0, a1, a2, a3, a4, a5);
    #pragma unroll 1
    for (int cc = 0; cc < 16; cc += 2) {
        LOADROWS(cbase + cc + 1, n0, n1, n2, n3, n4, n5);
        COMPUTE(cbase + cc, a0, a1, a2, a3, a4, a5);
        if (cc + 2 < 16) LOADROWS(cbase + cc + 2, a0, a1, a2, a3, a4, a5);
        COMPUTE(cbase + cc + 1, n0, n1, n2, n3, n4, n5);
    }
#undef LOADROWS
#undef COMPUTE

    // deterministic cross-wave reduction; [wave][row][k][lane] layout keeps
    // lane stride at 8B (2-way bank aliasing = free).
    #pragma unroll
    for (int o = 0; o < 4; ++o)
        #pragma unroll
        for (int k = 0; k < 4; ++k)
            sred[w][o][k][lane] = acc[o][k];
    __syncthreads();

    const int row = w;                 // wave handles output row y0+w
    const double bv = bias[which];
    double* fp = f + (size_t)plane * PSZ + (size_t)(y0 + row) * W + lane * 4;
    #pragma unroll
    for (int k = 0; k < 4; ++k) {
        double s = sred[0][row][k][lane] + sred[1][row][k][lane]
                 + sred[2][row][k][lane] + sred[3][row][k][lane] + bv;
        fp[k] = 1.0 + 1.0 / (1.0 + exp(-s));
    }
}

// ---------------------------------------------------------------------------
// Selection. block = one (b,y) row; 256 threads = 64 float4-cols x 4 channel
// groups. f-row values live in registers, reused over 16 channels.
// ---------------------------------------------------------------------------
__global__ __launch_bounds__(256) void select_kernel(
    const float*  __restrict__ x0,
    const float*  __restrict__ x1,
    const double* __restrict__ f0,
    const double* __restrict__ f1,
    float* __restrict__ out,
    unsigned int* __restrict__ count1)
{
    const int by = blockIdx.x;        // 0 .. B*H-1
    const int b  = by >> 8;
    const int y  = by & (H - 1);
    const int tx = threadIdx.x & 63;
    const int tc = threadIdx.x >> 6;

    const size_t plane = (size_t)b * H * W + (size_t)y * W + (size_t)tx * 4;
    double g0[4], g1[4];
    #pragma unroll
    for (int j = 0; j < 4; ++j) { g0[j] = f0[plane + j]; g1[j] = f1[plane + j]; }

    const size_t rowbase = (size_t)b * C * H * W + (size_t)y * W + (size_t)tx * 4;

    unsigned int cnt = 0;
    for (int ci = tc; ci < C; ci += 4) {
        size_t off = rowbase + (size_t)ci * H * W;
        float4 a  = *(const float4*)(x0 + off);
        float4 bb = *(const float4*)(x1 + off);
        float4 r;
        { double w0=(double)a.x*g0[0], w1=(double)bb.x*g1[0]; bool s1=(w1>w0); cnt+=s1; r.x=s1?bb.x:a.x; }
        { double w0=(double)a.y*g0[1], w1=(double)bb.y*g1[1]; bool s1=(w1>w0); cnt+=s1; r.y=s1?bb.y:a.y; }
        { double w0=(double)a.z*g0[2], w1=(double)bb.z*g1[2]; bool s1=(w1>w0); cnt+=s1; r.z=s1?bb.z:a.z; }
        { double w0=(double)a.w*g0[3], w1=(double)bb.w*g1[3]; bool s1=(w1>w0); cnt+=s1; r.w=s1?bb.w:a.w; }
        *(float4*)(out + off) = r;
    }

    __shared__ unsigned int blk;
    if (threadIdx.x == 0) blk = 0;
    __syncthreads();
    atomicAdd(&blk, cnt);
    __syncthreads();
    if (threadIdx.x == 0) atomicAdd(count1, blk);
}

__global__ void finalize_kernel(const unsigned int* __restrict__ count1,
                                float* __restrict__ out_p)
{
    const double N = (double)B * C * H * W;
    double c1 = (double)(*count1);
    out_p[0] = (float)((N - c1) / N);
    out_p[1] = (float)(c1 / N);
}

extern "C" void kernel_launch(void* const* d_in, const int* in_sizes, int n_in,
                              void* d_out, int out_size, void* d_ws, size_t ws_size,
                              hipStream_t stream) {
    const float* x0    = (const float*)d_in[0];
    const float* x1    = (const float*)d_in[1];
    const float* dw_w0 = (const float*)d_in[2];
    const float* dw_b0 = (const float*)d_in[3];
    const float* pw_w0 = (const float*)d_in[4];
    const float* pw_b0 = (const float*)d_in[5];
    const float* dw_w1 = (const float*)d_in[6];
    const float* dw_b1 = (const float*)d_in[7];
    const float* pw_w1 = (const float*)d_in[8];
    const float* pw_b1 = (const float*)d_in[9];
    float* out = (float*)d_out;

    unsigned int* cnt  = (unsigned int*)d_ws;
    double*       wc   = (double*)((char*)d_ws + OFF_WC);
    double*       bias = (double*)((char*)d_ws + OFF_BIAS);
    double*       f    = (double*)((char*)d_ws + OFF_F);
    double*       f0   = f;                       // planes 0..7  (input 0)
    double*       f1   = f + (size_t)8 * PSZ;     // planes 8..15 (input 1)

    hipMemsetAsync(d_ws, 0, 256, stream);

    prep_kernel<<<1, 128, 0, stream>>>(dw_w0, dw_b0, pw_w0, pw_b0,
                                       dw_w1, dw_b1, pw_w1, pw_b1, wc, bias);

    score_band_kernel<<<NPLANE * (H / 4), 256, 0, stream>>>(x0, x1, wc, bias, f);

    select_kernel<<<B * H, 256, 0, stream>>>(x0, x1, f0, f1, out, cnt);

    finalize_kernel<<<1, 1, 0, stream>>>(cnt, out + (size_t)B * C * H * W);
}